// Round 13
// baseline (130.167 us; speedup 1.0000x reference)
//
#include <hip/hip_runtime.h>
#include <cstddef>
#include <cstdint>

constexpr int BATCH   = 4096;
constexpr int IN_DIM  = 8192;
constexpr int OUT_DIM = 16384;
constexpr int THREADS = 1024;                       // 16 waves per block
constexpr int ROWS    = 16;                         // rows per block
constexpr int QUADS   = ROWS / 4;                   // 4 pipeline steps of 4 rows
constexpr int NBLK    = BATCH / ROWS;               // 256 blocks -> 1 per CU
constexpr int OPT     = 4;                          // neurons per thread per chunk
constexpr int CHUNKS  = OUT_DIM / (THREADS * OPT);  // 4
constexpr int SSTEPS  = (IN_DIM / 4) / THREADS;     // 2 f32x4 loads per row per thread

typedef float    f32x4 __attribute__((ext_vector_type(4)));
typedef uint32_t u32x2 __attribute__((ext_vector_type(2)));

__device__ __forceinline__ uint32_t f2bf(float f) {   // RNE bf16 (x in [0,1))
  uint32_t u = __float_as_uint(f);
  u += 0x7fffu + ((u >> 16) & 1u);
  return u >> 16;
}
__device__ __forceinline__ uint32_t pack_bf(float a, float b) {
  return f2bf(a) | (f2bf(b) << 16);
}
__device__ __forceinline__ float bf_lo(uint32_t u) { return __uint_as_float(u << 16); }
__device__ __forceinline__ float bf_hi(uint32_t u) { return __uint_as_float(u & 0xffff0000u); }

// softmax over 16 gate logits collapsed to (c0, ca, cb, cab); also packs idx pair
__global__ __launch_bounds__(64)
void coef_kernel(const float* __restrict__ weights,
                 const int* __restrict__ idx_a,
                 const int* __restrict__ idx_b,
                 float4* __restrict__ coef,
                 uint32_t* __restrict__ pidx) {
  const int o = blockIdx.x * 64 + threadIdx.x;
  if (o >= OUT_DIM) return;

  const float4* wp = reinterpret_cast<const float4*>(weights + (size_t)o * 16);
  float4 t0 = wp[0], t1 = wp[1], t2 = wp[2], t3 = wp[3];
  float w[16] = { t0.x, t0.y, t0.z, t0.w, t1.x, t1.y, t1.z, t1.w,
                  t2.x, t2.y, t2.z, t2.w, t3.x, t3.y, t3.z, t3.w };
  float m = w[0];
#pragma unroll
  for (int i = 1; i < 16; ++i) m = fmaxf(m, w[i]);
  float p[16]; float s = 0.f;
#pragma unroll
  for (int i = 0; i < 16; ++i) { p[i] = __expf(w[i] - m); s += p[i]; }
  const float inv = 1.0f / s;
  const float GC[16]  = {0,0,0,0, 0,0,0,0, 1,1,1,1, 1,1,1,1};
  const float GA[16]  = {0,0,1,1, 0,0,1,1, -1,-1,0,0, -1,-1,0,0};
  const float GB[16]  = {0,0,0,0, 1,1,1,1, -1,-1,-1,-1, 0,0,0,0};
  const float GAB[16] = {0,1,-1,0, -1,0,-2,-1, 1,2,0,1, 0,1,-1,0};
  float c0 = 0.f, ca = 0.f, cb = 0.f, cab = 0.f;
#pragma unroll
  for (int i = 0; i < 16; ++i) {
    c0 += p[i] * GC[i]; ca += p[i] * GA[i];
    cb += p[i] * GB[i]; cab += p[i] * GAB[i];
  }
  coef[o] = make_float4(c0 * inv, ca * inv, cb * inv, cab * inv);
  pidx[o] = (uint32_t)idx_a[o] | ((uint32_t)idx_b[o] << 16);
}

// 2-row affine eval from one packed bf16-pair of a and b; returns {lo-row, hi-row}
__device__ __forceinline__ float2 eval2(float4 c, uint32_t ga, uint32_t gb) {
  const float a0 = bf_lo(ga), b0 = bf_lo(gb);
  const float a1 = bf_hi(ga), b1 = bf_hi(gb);
  float2 r;
  r.x = fmaf(fmaf(c.w, a0, c.z), b0, fmaf(c.y, a0, c.x));
  r.y = fmaf(fmaf(c.w, a1, c.z), b1, fmaf(c.y, a1, c.x));
  return r;
}

__global__ __launch_bounds__(THREADS, 4)            // VGPR<=128
void logic_main(const float* __restrict__ x,
                const float4* __restrict__ coef,
                const uint32_t* __restrict__ pidx,
                float* __restrict__ out) {
  // double-buffered 4-row packs: buf[i] = { bf(r0)|bf(r1)<<16 , bf(r2)|bf(r3)<<16 }
  __shared__ u32x2 bufA[IN_DIM];                    // 64 KB
  __shared__ u32x2 bufB[IN_DIM];                    // 64 KB  -> 128 KB, 1 block/CU

  const int t    = threadIdx.x;
  const int row0 = blockIdx.x * ROWS;

  f32x4 la[SSTEPS], lb[SSTEPS], lc[SSTEPS], ld[SSTEPS];  // in-flight quad (32 VGPR)

  // ---- prologue: load + pack quad 0 into bufA ----
  {
    const f32x4* __restrict__ rA =
        reinterpret_cast<const f32x4*>(x + (size_t)(row0 + 0) * IN_DIM);
    const f32x4* __restrict__ rB =
        reinterpret_cast<const f32x4*>(x + (size_t)(row0 + 1) * IN_DIM);
    const f32x4* __restrict__ rC =
        reinterpret_cast<const f32x4*>(x + (size_t)(row0 + 2) * IN_DIM);
    const f32x4* __restrict__ rD =
        reinterpret_cast<const f32x4*>(x + (size_t)(row0 + 3) * IN_DIM);
#pragma unroll
    for (int s = 0; s < SSTEPS; ++s) {
      const int q = s * THREADS + t;
      la[s] = rA[q]; lb[s] = rB[q]; lc[s] = rC[q]; ld[s] = rD[q];
    }
#pragma unroll
    for (int s = 0; s < SSTEPS; ++s) {
      const int q = s * THREADS + t;
      u32x2 p0, p1, p2, p3;
      p0.x = pack_bf(la[s].x, lb[s].x); p0.y = pack_bf(lc[s].x, ld[s].x);
      p1.x = pack_bf(la[s].y, lb[s].y); p1.y = pack_bf(lc[s].y, ld[s].y);
      p2.x = pack_bf(la[s].z, lb[s].z); p2.y = pack_bf(lc[s].z, ld[s].z);
      p3.x = pack_bf(la[s].w, lb[s].w); p3.y = pack_bf(lc[s].w, ld[s].w);
      bufA[4 * q + 0] = p0; bufA[4 * q + 1] = p1;
      bufA[4 * q + 2] = p2; bufA[4 * q + 3] = p3;
    }
  }
  __syncthreads();

  for (int qd = 0; qd < QUADS; ++qd) {
    const int bLo = row0 + 4 * qd;
    const u32x2* __restrict__ buf = (qd & 1) ? bufB : bufA;
    u32x2* __restrict__ nxt = (qd & 1) ? bufA : bufB;

    // ---- ISSUE next quad's loads; pin them ahead of the compute ----
    if (qd + 1 < QUADS) {
      const f32x4* __restrict__ rA =
          reinterpret_cast<const f32x4*>(x + (size_t)(bLo + 4) * IN_DIM);
      const f32x4* __restrict__ rB =
          reinterpret_cast<const f32x4*>(x + (size_t)(bLo + 5) * IN_DIM);
      const f32x4* __restrict__ rC =
          reinterpret_cast<const f32x4*>(x + (size_t)(bLo + 6) * IN_DIM);
      const f32x4* __restrict__ rD =
          reinterpret_cast<const f32x4*>(x + (size_t)(bLo + 7) * IN_DIM);
#pragma unroll
      for (int s = 0; s < SSTEPS; ++s) {
        const int q = s * THREADS + t;
        la[s] = rA[q]; lb[s] = rB[q]; lc[s] = rC[q]; ld[s] = rD[q];
      }
      __builtin_amdgcn_sched_barrier(0);   // loads issued BEFORE compute below
    }

    // ---- compute current quad: gather + affine + stores ----
    {
      int o0 = t * OPT;
      int4   pi = *reinterpret_cast<const int4*>(pidx + o0);
      float4 c0 = coef[o0 + 0], c1 = coef[o0 + 1],
             c2 = coef[o0 + 2], c3 = coef[o0 + 3];

#pragma unroll
      for (int ch = 0; ch < CHUNKS; ++ch) {
        const int o = ch * (THREADS * OPT) + t * OPT;

        const uint32_t i0a = (uint32_t)pi.x & 0xffffu, i0b = (uint32_t)pi.x >> 16;
        const uint32_t i1a = (uint32_t)pi.y & 0xffffu, i1b = (uint32_t)pi.y >> 16;
        const uint32_t i2a = (uint32_t)pi.z & 0xffffu, i2b = (uint32_t)pi.z >> 16;
        const uint32_t i3a = (uint32_t)pi.w & 0xffffu, i3b = (uint32_t)pi.w >> 16;

        const u32x2 g0a = buf[i0a], g0b = buf[i0b];
        const u32x2 g1a = buf[i1a], g1b = buf[i1b];
        const u32x2 g2a = buf[i2a], g2b = buf[i2b];
        const u32x2 g3a = buf[i3a], g3b = buf[i3b];

        const float2 e0lo = eval2(c0, g0a.x, g0b.x), e0hi = eval2(c0, g0a.y, g0b.y);
        const float2 e1lo = eval2(c1, g1a.x, g1b.x), e1hi = eval2(c1, g1a.y, g1b.y);
        const float2 e2lo = eval2(c2, g2a.x, g2b.x), e2hi = eval2(c2, g2a.y, g2b.y);
        const float2 e3lo = eval2(c3, g3a.x, g3b.x), e3hi = eval2(c3, g3a.y, g3b.y);

        f32x4 res0, res1, res2, res3;
        res0.x = e0lo.x; res0.y = e1lo.x; res0.z = e2lo.x; res0.w = e3lo.x;
        res1.x = e0lo.y; res1.y = e1lo.y; res1.z = e2lo.y; res1.w = e3lo.y;
        res2.x = e0hi.x; res2.y = e1hi.x; res2.z = e2hi.x; res2.w = e3hi.x;
        res3.x = e0hi.y; res3.y = e1hi.y; res3.z = e2hi.y; res3.w = e3hi.y;

        if (ch + 1 < CHUNKS) {
          const int on = o + THREADS * OPT;
          pi = *reinterpret_cast<const int4*>(pidx + on);
          c0 = coef[on + 0]; c1 = coef[on + 1];
          c2 = coef[on + 2]; c3 = coef[on + 3];
        }

        *reinterpret_cast<f32x4*>(out + (size_t)(bLo + 0) * OUT_DIM + o) = res0;
        *reinterpret_cast<f32x4*>(out + (size_t)(bLo + 1) * OUT_DIM + o) = res1;
        *reinterpret_cast<f32x4*>(out + (size_t)(bLo + 2) * OUT_DIM + o) = res2;
        *reinterpret_cast<f32x4*>(out + (size_t)(bLo + 3) * OUT_DIM + o) = res3;
      }
    }

    // ---- pack + write next quad (loads drained under compute); one barrier ----
    if (qd + 1 < QUADS) {
#pragma unroll
      for (int s = 0; s < SSTEPS; ++s) {
        const int q = s * THREADS + t;
        u32x2 p0, p1, p2, p3;
        p0.x = pack_bf(la[s].x, lb[s].x); p0.y = pack_bf(lc[s].x, ld[s].x);
        p1.x = pack_bf(la[s].y, lb[s].y); p1.y = pack_bf(lc[s].y, ld[s].y);
        p2.x = pack_bf(la[s].z, lb[s].z); p2.y = pack_bf(lc[s].z, ld[s].z);
        p3.x = pack_bf(la[s].w, lb[s].w); p3.y = pack_bf(lc[s].w, ld[s].w);
        nxt[4 * q + 0] = p0; nxt[4 * q + 1] = p1;
        nxt[4 * q + 2] = p2; nxt[4 * q + 3] = p3;
      }
      __syncthreads();
    }
  }
}

extern "C" void kernel_launch(void* const* d_in, const int* in_sizes, int n_in,
                              void* d_out, int out_size, void* d_ws, size_t ws_size,
                              hipStream_t stream) {
  const float* x       = (const float*)d_in[0];
  const float* weights = (const float*)d_in[1];
  const int*   idx_a   = (const int*)d_in[2];
  const int*   idx_b   = (const int*)d_in[3];
  float*       out     = (float*)d_out;

  float4*   coef = (float4*)d_ws;                                   // 256 KB
  uint32_t* pidx = (uint32_t*)((char*)d_ws + (size_t)OUT_DIM * 16); // +64 KB

  coef_kernel<<<OUT_DIM / 64, 64, 0, stream>>>(weights, idx_a, idx_b, coef, pidx);
  logic_main<<<NBLK, THREADS, 0, stream>>>(x, coef, pidx, out);
}

// Round 14
// 111.578 us; speedup vs baseline: 1.1666x; 1.1666x over previous
//
#include <hip/hip_runtime.h>
#include <cstddef>
#include <cstdint>

constexpr int BATCH   = 4096;
constexpr int IN_DIM  = 8192;
constexpr int OUT_DIM = 16384;
constexpr int THREADS = 512;                        // 8 waves per block
constexpr int RPB     = 2;                          // rows per block (fp32 in LDS)
constexpr int NBLK    = BATCH / RPB;                // 2048 blocks -> 2/CU resident
constexpr int OPT     = 4;                          // neurons per thread per chunk
constexpr int CHUNKS  = OUT_DIM / (THREADS * OPT);  // 8

typedef float f32x4 __attribute__((ext_vector_type(4)));

// async 16-byte global->LDS DMA (no VGPR round-trip, no pack VALU)
__device__ __forceinline__ void dma16(const float* g, float* l) {
  __builtin_amdgcn_global_load_lds(
      (const __attribute__((address_space(1))) uint32_t*)g,
      (__attribute__((address_space(3))) uint32_t*)l, 16, 0, 0);
}

// softmax over 16 gate logits collapsed to (c0, ca, cb, cab); also packs idx pair
__global__ __launch_bounds__(64)
void coef_kernel(const float* __restrict__ weights,
                 const int* __restrict__ idx_a,
                 const int* __restrict__ idx_b,
                 float4* __restrict__ coef,
                 uint32_t* __restrict__ pidx) {
  const int o = blockIdx.x * 64 + threadIdx.x;
  if (o >= OUT_DIM) return;

  const float4* wp = reinterpret_cast<const float4*>(weights + (size_t)o * 16);
  float4 t0 = wp[0], t1 = wp[1], t2 = wp[2], t3 = wp[3];
  float w[16] = { t0.x, t0.y, t0.z, t0.w, t1.x, t1.y, t1.z, t1.w,
                  t2.x, t2.y, t2.z, t2.w, t3.x, t3.y, t3.z, t3.w };
  float m = w[0];
#pragma unroll
  for (int i = 1; i < 16; ++i) m = fmaxf(m, w[i]);
  float p[16]; float s = 0.f;
#pragma unroll
  for (int i = 0; i < 16; ++i) { p[i] = __expf(w[i] - m); s += p[i]; }
  const float inv = 1.0f / s;
  const float GC[16]  = {0,0,0,0, 0,0,0,0, 1,1,1,1, 1,1,1,1};
  const float GA[16]  = {0,0,1,1, 0,0,1,1, -1,-1,0,0, -1,-1,0,0};
  const float GB[16]  = {0,0,0,0, 1,1,1,1, -1,-1,-1,-1, 0,0,0,0};
  const float GAB[16] = {0,1,-1,0, -1,0,-2,-1, 1,2,0,1, 0,1,-1,0};
  float c0 = 0.f, ca = 0.f, cb = 0.f, cab = 0.f;
#pragma unroll
  for (int i = 0; i < 16; ++i) {
    c0 += p[i] * GC[i]; ca += p[i] * GA[i];
    cb += p[i] * GB[i]; cab += p[i] * GAB[i];
  }
  coef[o] = make_float4(c0 * inv, ca * inv, cb * inv, cab * inv);
  pidx[o] = (uint32_t)idx_a[o] | ((uint32_t)idx_b[o] << 16);
}

__global__ __launch_bounds__(THREADS)
void logic_main(const float* __restrict__ x,
                const float4* __restrict__ coef,
                const uint32_t* __restrict__ pidx,
                float* __restrict__ out) {
  __shared__ float rowA[IN_DIM];                    // 32 KB (fp32 row b0)
  __shared__ float rowB[IN_DIM];                    // 32 KB (fp32 row b0+1) -> 2 blocks/CU

  const int t    = threadIdx.x;
  const int lane = t & 63;
  const int wv   = t >> 6;                          // wave id 0..7
  const int b0   = blockIdx.x * RPB;

  // ---- stage 2 rows via async DMA: 8 waves x 4 segments x 1024 B per row ----
  {
    const float* __restrict__ src0 = x + (size_t)b0 * IN_DIM;
    const float* __restrict__ src1 = x + (size_t)(b0 + 1) * IN_DIM;
#pragma unroll
    for (int s = 0; s < 4; ++s) {
      const int off = (wv * 4 + s) * 256 + lane * 4;   // float index, 16B per lane
      dma16(src0 + off, rowA + off);
      dma16(src1 + off, rowB + off);
    }
  }

  // prefetch chunk-0 operands while DMA is in flight
  int o0 = t * OPT;
  int4   pi = *reinterpret_cast<const int4*>(pidx + o0);
  float4 c0 = coef[o0 + 0], c1 = coef[o0 + 1],
         c2 = coef[o0 + 2], c3 = coef[o0 + 3];

  __syncthreads();                                  // drains DMA (vmcnt) + barrier

#pragma unroll 2
  for (int ch = 0; ch < CHUNKS; ++ch) {
    const int o = ch * (THREADS * OPT) + t * OPT;

    const uint32_t i0a = (uint32_t)pi.x & 0xffffu, i0b = (uint32_t)pi.x >> 16;
    const uint32_t i1a = (uint32_t)pi.y & 0xffffu, i1b = (uint32_t)pi.y >> 16;
    const uint32_t i2a = (uint32_t)pi.z & 0xffffu, i2b = (uint32_t)pi.z >> 16;
    const uint32_t i3a = (uint32_t)pi.w & 0xffffu, i3b = (uint32_t)pi.w >> 16;

    // 16 ds_read_b32 gathers (4 per output: a,b from each of 2 rows)
    const float a0A = rowA[i0a], b0A = rowA[i0b], a0B = rowB[i0a], b0B = rowB[i0b];
    const float a1A = rowA[i1a], b1A = rowA[i1b], a1B = rowB[i1a], b1B = rowB[i1b];
    const float a2A = rowA[i2a], b2A = rowA[i2b], a2B = rowB[i2a], b2B = rowB[i2b];
    const float a3A = rowA[i3a], b3A = rowA[i3b], a3B = rowB[i3a], b3B = rowB[i3b];

    f32x4 resA, resB;
    resA.x = fmaf(fmaf(c0.w, a0A, c0.z), b0A, fmaf(c0.y, a0A, c0.x));
    resB.x = fmaf(fmaf(c0.w, a0B, c0.z), b0B, fmaf(c0.y, a0B, c0.x));
    resA.y = fmaf(fmaf(c1.w, a1A, c1.z), b1A, fmaf(c1.y, a1A, c1.x));
    resB.y = fmaf(fmaf(c1.w, a1B, c1.z), b1B, fmaf(c1.y, a1B, c1.x));
    resA.z = fmaf(fmaf(c2.w, a2A, c2.z), b2A, fmaf(c2.y, a2A, c2.x));
    resB.z = fmaf(fmaf(c2.w, a2B, c2.z), b2B, fmaf(c2.y, a2B, c2.x));
    resA.w = fmaf(fmaf(c3.w, a3A, c3.z), b3A, fmaf(c3.y, a3A, c3.x));
    resB.w = fmaf(fmaf(c3.w, a3B, c3.z), b3B, fmaf(c3.y, a3B, c3.x));

    // prefetch next chunk's operands before the stores
    if (ch + 1 < CHUNKS) {
      const int on = o + THREADS * OPT;
      pi = *reinterpret_cast<const int4*>(pidx + on);
      c0 = coef[on + 0]; c1 = coef[on + 1];
      c2 = coef[on + 2]; c3 = coef[on + 3];
    }

    *reinterpret_cast<f32x4*>(out + (size_t)(b0 + 0) * OUT_DIM + o) = resA;
    *reinterpret_cast<f32x4*>(out + (size_t)(b0 + 1) * OUT_DIM + o) = resB;
  }
}

extern "C" void kernel_launch(void* const* d_in, const int* in_sizes, int n_in,
                              void* d_out, int out_size, void* d_ws, size_t ws_size,
                              hipStream_t stream) {
  const float* x       = (const float*)d_in[0];
  const float* weights = (const float*)d_in[1];
  const int*   idx_a   = (const int*)d_in[2];
  const int*   idx_b   = (const int*)d_in[3];
  float*       out     = (float*)d_out;

  float4*   coef = (float4*)d_ws;                                   // 256 KB
  uint32_t* pidx = (uint32_t*)((char*)d_ws + (size_t)OUT_DIM * 16); // +64 KB

  coef_kernel<<<OUT_DIM / 64, 64, 0, stream>>>(weights, idx_a, idx_b, coef, pidx);
  logic_main<<<NBLK, THREADS, 0, stream>>>(x, coef, pidx, out);
}